// Round 11
// baseline (7417.644 us; speedup 1.0000x reference)
//
#include <hip/hip_runtime.h>
#include <stdint.h>

// SingleBandLSTM: B=64, IN=16, H=512, T=1024, 2-layer LSTM, constant input per step.
// R11 = R10 (5963us) + three latency-chain cuts:
//  1. parallel polls: wave0=h0-ready, wave1=h1-ready, wave2=ring backpressure
//  2. per-producer seq-word ready flags (plain sc1 stores; no 32-way RMW
//     serialization on one counter). done/backpressure counters stay RMW (off-path).
//  3. packed publish: nonlin->hpk (2KB LDS) -> wave0 stores 64x32B coalesced sc1
//     + bare vmcnt(0) + seq-word store (R7-validated ordering pattern).
//     Ring layout now slice-contiguous: [slot][producer][batch][16 units bf16].
// Kept from R10: coalesced 8x dwordx4 sc1 staging in ONE self-contained asm block
// (loads + vmcnt(0) inside, early-clobber outputs), split L0/L1 blocks, ring depth 8,
// fused ih+hh MFMA, gbuf gate transpose, ((row&7)<<4) LDS swizzle.

#define TSEQ 1024
#define HDIM 512
#define BATCH 64
#define RING 8

typedef __attribute__((ext_vector_type(8))) short bf16x8;
typedef __attribute__((ext_vector_type(4))) float f32x4;
typedef __attribute__((ext_vector_type(4))) unsigned int u32x4;
typedef unsigned long long u64;

__device__ __forceinline__ unsigned short f2bf(float f) {
  union { float f; unsigned u; } v; v.f = f;
  unsigned r = v.u + 0x7FFFu + ((v.u >> 16) & 1u);   // RNE
  return (unsigned short)(r >> 16);
}
__device__ __forceinline__ float bf2f(unsigned short s) {
  union { unsigned u; float f; } v; v.u = ((unsigned)s) << 16; return v.f;
}
__device__ __forceinline__ float sigm(float x) { return 1.0f / (1.0f + __expf(-x)); }
__device__ __forceinline__ float tanh_(float x) { return 1.0f - 2.0f / (__expf(2.0f * x) + 1.0f); }

__device__ __forceinline__ int g_ld32(const int* p) {
  return __hip_atomic_load(p, __ATOMIC_RELAXED, __HIP_MEMORY_SCOPE_AGENT);
}
__device__ __forceinline__ void g_st32(int* p, int v) {
  __hip_atomic_store(p, v, __ATOMIC_RELAXED, __HIP_MEMORY_SCOPE_AGENT);
}
__device__ __forceinline__ void g_st64(u64* p, u64 v) {
  __hip_atomic_store(p, v, __ATOMIC_RELAXED, __HIP_MEMORY_SCOPE_AGENT);
}
__device__ __forceinline__ void flag_add(int* p) {
  __hip_atomic_fetch_add(p, 1, __ATOMIC_RELAXED, __HIP_MEMORY_SCOPE_AGENT);
}
__device__ __forceinline__ void flag_wait(int* p, int target) {
  while (g_ld32(p) < target) __builtin_amdgcn_s_sleep(1);
}
// Poll 32 per-producer seq words (16B stride): pass when all >= tgt.
__device__ __forceinline__ void poll_seq(const int* f, int tgt, int lane) {
  const int* a = f + (lane & 31) * 4;
  while (!__all(g_ld32(a) >= tgt)) __builtin_amdgcn_s_sleep(1);
}

// Stage 64KB ring slot [32 prod][64 b][16 units bf16] -> LDS [b][512u] with byte-col
// XOR ((b&7)<<4). 8x dwordx4 sc1 + vmcnt(0) in ONE asm block (R4-safe).
// Quad q (16B): producer q>>7, batch (q>>1)&63, unit-half q&1 -> col16 = (q>>7)*2+(q&1).
__device__ __forceinline__ void stage64k(char* lds, const unsigned short* src, int tid) {
  u32x4 r0, r1, r2, r3, r4, r5, r6, r7;
  const char* a = (const char*)src + (size_t)tid * 16;
  asm volatile(
      "global_load_dwordx4 %0, %8, off sc1\n\t"
      "global_load_dwordx4 %1, %9, off sc1\n\t"
      "global_load_dwordx4 %2, %10, off sc1\n\t"
      "global_load_dwordx4 %3, %11, off sc1\n\t"
      "global_load_dwordx4 %4, %12, off sc1\n\t"
      "global_load_dwordx4 %5, %13, off sc1\n\t"
      "global_load_dwordx4 %6, %14, off sc1\n\t"
      "global_load_dwordx4 %7, %15, off sc1\n\t"
      "s_waitcnt vmcnt(0)"
      : "=&v"(r0), "=&v"(r1), "=&v"(r2), "=&v"(r3),
        "=&v"(r4), "=&v"(r5), "=&v"(r6), "=&v"(r7)
      : "v"(a), "v"(a + 8192), "v"(a + 16384), "v"(a + 24576),
        "v"(a + 32768), "v"(a + 40960), "v"(a + 49152), "v"(a + 57344)
      : "memory");
  u32x4 vv[8] = {r0, r1, r2, r3, r4, r5, r6, r7};
  #pragma unroll
  for (int i = 0; i < 8; ++i) {
    int q = tid + i * 512;
    int b = (q >> 1) & 63;
    int col = (((q >> 7) << 5) | ((q & 1) << 4)) ^ ((b & 7) << 4);
    *(u32x4*)(lds + b * 1024 + col) = vv[i];
  }
}
__device__ __forceinline__ void zero64k(char* lds, int tid) {
  u32x4 z = {0u, 0u, 0u, 0u};
  #pragma unroll
  for (int i = 0; i < 8; ++i)
    *(u32x4*)(lds + (size_t)(tid + i * 512) * 16) = z;
}

// Packed publish: wave 0, lane b stores its 32B hpk row; drain; lane0 seq-word.
__device__ __forceinline__ void publish2k(char* slotbase, int p, const unsigned short* hpk,
                                          int lane, int* flagword, int val) {
  const u64* s = (const u64*)(hpk + lane * 16);
  u64 v0 = s[0], v1 = s[1], v2 = s[2], v3 = s[3];
  u64* d = (u64*)(slotbase + p * 2048 + lane * 32);
  g_st64(d + 0, v0); g_st64(d + 1, v1); g_st64(d + 2, v2); g_st64(d + 3, v3);
  asm volatile("s_waitcnt vmcnt(0)" ::: "memory");   // data at LLC before flag
  if (lane == 0) g_st32(flagword, val);
}

// ---------------- precompute kernels ----------------
__global__ void k_fc_in(const float* __restrict__ x, const float* __restrict__ w_in,
                        const float* __restrict__ b_in, float* __restrict__ h_in) {
  int b = blockIdx.x;      // 64
  int j = threadIdx.x;     // 512
  float acc = b_in[j];
  #pragma unroll
  for (int i = 0; i < 16; ++i) acc += x[b * 16 + i] * w_in[j * 16 + i];
  h_in[b * HDIM + j] = acc;
}

__global__ __launch_bounds__(512, 1)
void k_xg0(const float* __restrict__ h_in, const float* __restrict__ w_ih0,
           const float* __restrict__ b_ih0, const float* __restrict__ b_hh0,
           float* __restrict__ xg0) {
  __shared__ float hbuf[64 * 516];
  __shared__ float wbuf[8 * 520];
  int r0 = blockIdx.x * 8;           // 256 blocks x 8 rows = 2048 gate rows
  int tid = threadIdx.x;
  for (int i = 0; i < 64; ++i) {
    int c = tid + i * 512;
    hbuf[(c >> 9) * 516 + (c & 511)] = h_in[c];
  }
  for (int i = 0; i < 8; ++i) {
    int c = tid + i * 512;
    wbuf[(c >> 9) * 520 + (c & 511)] = w_ih0[(size_t)r0 * HDIM + c];
  }
  __syncthreads();
  int b = tid >> 3, rl = tid & 7;
  float acc = 0.f;
  for (int k = 0; k < 512; ++k) acc += hbuf[b * 516 + k] * wbuf[rl * 520 + k];
  int r = r0 + rl;
  xg0[(size_t)b * 2048 + r] = acc + b_ih0[r] + b_hh0[r];
}

// ---------------- persistent recurrence kernel ----------------
__global__ __launch_bounds__(512, 1)
void lstm_persist(const float* __restrict__ w_hh0,
                  const float* __restrict__ w_ih1,
                  const float* __restrict__ w_hh1,
                  const float* __restrict__ b_ih1,
                  const float* __restrict__ b_hh1,
                  const float* __restrict__ w_out,
                  const float* __restrict__ b_out,
                  const float* __restrict__ xg0,
                  unsigned short* __restrict__ ring0,
                  unsigned short* __restrict__ ring1,
                  int* __restrict__ flags,
                  float* __restrict__ out) {
  __shared__ __align__(16) unsigned short hA[BATCH * HDIM];  // 64KB swizzled
  __shared__ __align__(16) unsigned short hBt[BATCH * HDIM]; // 64KB swizzled
  __shared__ float gbuf[BATCH * 68];
  __shared__ __align__(16) unsigned short hpk[BATCH * 16];   // 2KB publish staging
  __shared__ float wout_s[HDIM];
  char* hAc = (char*)hA;
  char* hBc = (char*)hBt;

  const int tid = threadIdx.x;
  const int layer = blockIdx.x & 1;
  const int p = blockIdx.x >> 1;      // 0..31 within group
  const int u0 = p * 16;              // first owned hidden unit

  const int wave = tid >> 6, lane = tid & 63;
  const int nt = wave & 3;            // N-tile (16 gate rows)
  const int mh = wave >> 2;           // M-tile pair selector
  const int ln15 = lane & 15, lg = lane >> 4;

  const int n_local = nt * 16 + ln15;
  const int grow = (n_local & 3) * HDIM + u0 + (n_local >> 2);  // global gate row

  int* f0 = flags;                    // 32 seq words x 16B stride
  int* f1 = flags + 128;
  int* h0_done = flags + 256;         // TSEQ counters (RMW, off-path)
  int* h1_done = flags + 256 + TSEQ;

  wout_s[tid] = w_out[tid];
  const float bout = b_out[0];

  // ---- weight fragments into registers (fp32 -> bf16) ----
  bf16x8 wh[16];
  bf16x8 wi[16];
  {
    const float* Wh = (layer == 0 ? w_hh0 : w_hh1) + (size_t)grow * HDIM;
    #pragma unroll
    for (int kt = 0; kt < 16; ++kt) {
      const float* s = Wh + kt * 32 + lg * 8;
      bf16x8 r;
      #pragma unroll
      for (int e = 0; e < 8; ++e) r[e] = (short)f2bf(s[e]);
      wh[kt] = r;
    }
  }
  if (layer == 1) {
    const float* Wi = w_ih1 + (size_t)grow * HDIM;
    #pragma unroll
    for (int kt = 0; kt < 16; ++kt) {
      const float* s = Wi + kt * 32 + lg * 8;
      bf16x8 r;
      #pragma unroll
      for (int e = 0; e < 8; ++e) r[e] = (short)f2bf(s[e]);
      wi[kt] = r;
    }
  }

  // ---- accumulator init ----
  f32x4 init0, init1;
  if (layer == 0) {
    #pragma unroll
    for (int r = 0; r < 4; ++r) {
      init0[r] = xg0[(size_t)(mh * 32 + lg * 4 + r) * 2048 + grow];
      init1[r] = xg0[(size_t)(mh * 32 + 16 + lg * 4 + r) * 2048 + grow];
    }
  } else {
    float bv = b_ih1[grow] + b_hh1[grow];
    #pragma unroll
    for (int r = 0; r < 4; ++r) { init0[r] = bv; init1[r] = bv; }
  }

  float c0 = 0.f, c1 = 0.f;
  const int pb = tid >> 3;            // nonlin ownership: batch
  const int pu = (tid << 1) & 15;     // unit_local (even)

  const int r0 = mh * 32 + ln15, r1 = r0 + 16;
  const int x0 = (r0 & 7) << 4, x1 = (r1 & 7) << 4;

  const int ob = tid >> 2, oseg = tid & 3;   // out-dot (tid<256)
  const int oxs = (ob & 7) << 4;

  if (layer == 0) {
    for (int t = 0; t < TSEQ; ++t) {
      if (wave == 0) { if (t > 0) poll_seq(f0, t, lane); }
      else if (wave == 1 && lane == 0 && t >= RING) flag_wait(&h0_done[t - RING], 64);
      __syncthreads();                                         // B1
      if (t > 0) stage64k(hAc, ring0 + (size_t)((t - 1) & (RING - 1)) * (BATCH * HDIM), tid);
      else       zero64k(hAc, tid);
      __syncthreads();                                         // B2
      if (tid == 0 && t > 0) flag_add(&h0_done[t - 1]);

      f32x4 a0 = init0, a1 = init1;
      #pragma unroll
      for (int kt = 0; kt < 16; ++kt) {
        const int kb = kt * 64 + lg * 16;
        bf16x8 ha0 = *(const bf16x8*)(hAc + r0 * 1024 + (kb ^ x0));
        bf16x8 ha1 = *(const bf16x8*)(hAc + r1 * 1024 + (kb ^ x1));
        a0 = __builtin_amdgcn_mfma_f32_16x16x32_bf16(ha0, wh[kt], a0, 0, 0, 0);
        a1 = __builtin_amdgcn_mfma_f32_16x16x32_bf16(ha1, wh[kt], a1, 0, 0, 0);
      }
      #pragma unroll
      for (int r = 0; r < 4; ++r) {
        gbuf[(mh * 32 + lg * 4 + r) * 68 + n_local] = a0[r];
        gbuf[(mh * 32 + 16 + lg * 4 + r) * 68 + n_local] = a1[r];
      }
      __syncthreads();                                         // B3
      {
        f32x4 gA = *(const f32x4*)&gbuf[pb * 68 + pu * 4];
        f32x4 gB = *(const f32x4*)&gbuf[pb * 68 + pu * 4 + 4];
        float i0 = sigm(gA[0]), f0v = sigm(gA[1]), z0 = tanh_(gA[2]), o0 = sigm(gA[3]);
        float i1 = sigm(gB[0]), f1v = sigm(gB[1]), z1 = tanh_(gB[2]), o1 = sigm(gB[3]);
        c0 = f0v * c0 + i0 * z0;
        c1 = f1v * c1 + i1 * z1;
        unsigned pk = (unsigned)f2bf(o0 * tanh_(c0)) | ((unsigned)f2bf(o1 * tanh_(c1)) << 16);
        *(unsigned*)&hpk[pb * 16 + pu] = pk;
      }
      __syncthreads();                                         // B4
      if (wave == 0)
        publish2k((char*)(ring0 + (size_t)(t & (RING - 1)) * (BATCH * HDIM)),
                  p, hpk, lane, &f0[p * 4], t + 1);
    }
  } else {
    for (int t = 0; t < TSEQ; ++t) {
      if (wave == 0) poll_seq(f0, t + 1, lane);
      else if (wave == 1) { if (t > 0) poll_seq(f1, t, lane); }
      else if (wave == 2 && lane == 0 && t >= RING) flag_wait(&h1_done[t - RING], 32);
      __syncthreads();                                         // B1
      stage64k(hAc, ring0 + (size_t)(t & (RING - 1)) * (BATCH * HDIM), tid);
      if (t > 0) stage64k(hBc, ring1 + (size_t)((t - 1) & (RING - 1)) * (BATCH * HDIM), tid);
      else       zero64k(hBc, tid);
      __syncthreads();                                         // B2
      if (tid == 0) {
        flag_add(&h0_done[t]);
        if (t > 0) flag_add(&h1_done[t - 1]);
      }

      // out[:, t-1] from hB = h1[t-1] (256 threads, parallel with MFMA below)
      if (t > 0 && tid < 256) {
        float od = 0.f;
        #pragma unroll
        for (int j = 0; j < 16; ++j) {
          const int c = (j * 4 + oseg) * 16;
          bf16x8 hv = *(const bf16x8*)(hBc + ob * 1024 + (c ^ oxs));
          const float* wo = &wout_s[c >> 1];
          #pragma unroll
          for (int e = 0; e < 8; ++e) od += bf2f((unsigned short)hv[e]) * wo[e];
        }
        od += __shfl_xor(od, 1);
        od += __shfl_xor(od, 2);
        if (oseg == 0) out[ob * TSEQ + (t - 1)] = od + bout;
      }

      f32x4 a0 = init0, a1 = init1;
      #pragma unroll
      for (int kt = 0; kt < 16; ++kt) {
        const int kb = kt * 64 + lg * 16;
        bf16x8 ia0 = *(const bf16x8*)(hAc + r0 * 1024 + (kb ^ x0));
        bf16x8 ia1 = *(const bf16x8*)(hAc + r1 * 1024 + (kb ^ x1));
        bf16x8 ha0 = *(const bf16x8*)(hBc + r0 * 1024 + (kb ^ x0));
        bf16x8 ha1 = *(const bf16x8*)(hBc + r1 * 1024 + (kb ^ x1));
        a0 = __builtin_amdgcn_mfma_f32_16x16x32_bf16(ia0, wi[kt], a0, 0, 0, 0);
        a1 = __builtin_amdgcn_mfma_f32_16x16x32_bf16(ia1, wi[kt], a1, 0, 0, 0);
        a0 = __builtin_amdgcn_mfma_f32_16x16x32_bf16(ha0, wh[kt], a0, 0, 0, 0);
        a1 = __builtin_amdgcn_mfma_f32_16x16x32_bf16(ha1, wh[kt], a1, 0, 0, 0);
      }
      #pragma unroll
      for (int r = 0; r < 4; ++r) {
        gbuf[(mh * 32 + lg * 4 + r) * 68 + n_local] = a0[r];
        gbuf[(mh * 32 + 16 + lg * 4 + r) * 68 + n_local] = a1[r];
      }
      __syncthreads();                                         // B3
      {
        f32x4 gA = *(const f32x4*)&gbuf[pb * 68 + pu * 4];
        f32x4 gB = *(const f32x4*)&gbuf[pb * 68 + pu * 4 + 4];
        float i0 = sigm(gA[0]), f0v = sigm(gA[1]), z0 = tanh_(gA[2]), o0 = sigm(gA[3]);
        float i1 = sigm(gB[0]), f1v = sigm(gB[1]), z1 = tanh_(gB[2]), o1 = sigm(gB[3]);
        c0 = f0v * c0 + i0 * z0;
        c1 = f1v * c1 + i1 * z1;
        unsigned pk = (unsigned)f2bf(o0 * tanh_(c0)) | ((unsigned)f2bf(o1 * tanh_(c1)) << 16);
        *(unsigned*)&hpk[pb * 16 + pu] = pk;
      }
      __syncthreads();                                         // B4
      if (wave == 0)
        publish2k((char*)(ring1 + (size_t)(t & (RING - 1)) * (BATCH * HDIM)),
                  p, hpk, lane, &f1[p * 4], t + 1);
    }
    // epilogue: out[:, T-1]
    if (wave == 0) poll_seq(f1, TSEQ, lane);
    __syncthreads();
    stage64k(hBc, ring1 + (size_t)((TSEQ - 1) & (RING - 1)) * (BATCH * HDIM), tid);
    __syncthreads();
    if (tid < 256) {
      float od = 0.f;
      #pragma unroll
      for (int j = 0; j < 16; ++j) {
        const int c = (j * 4 + oseg) * 16;
        bf16x8 hv = *(const bf16x8*)(hBc + ob * 1024 + (c ^ oxs));
        const float* wo = &wout_s[c >> 1];
        #pragma unroll
        for (int e = 0; e < 8; ++e) od += bf2f((unsigned short)hv[e]) * wo[e];
      }
      od += __shfl_xor(od, 1);
      od += __shfl_xor(od, 2);
      if (oseg == 0) out[ob * TSEQ + (TSEQ - 1)] = od + bout;
    }
  }
}

extern "C" void kernel_launch(void* const* d_in, const int* in_sizes, int n_in,
                              void* d_out, int out_size, void* d_ws, size_t ws_size,
                              hipStream_t stream) {
  (void)in_sizes; (void)n_in; (void)out_size; (void)ws_size;
  const float* x     = (const float*)d_in[0];
  const float* w_in  = (const float*)d_in[1];
  const float* b_in  = (const float*)d_in[2];
  const float* w_ih0 = (const float*)d_in[3];
  const float* w_hh0 = (const float*)d_in[4];
  const float* b_ih0 = (const float*)d_in[5];
  const float* b_hh0 = (const float*)d_in[6];
  const float* w_ih1 = (const float*)d_in[7];
  const float* w_hh1 = (const float*)d_in[8];
  const float* b_ih1 = (const float*)d_in[9];
  const float* b_hh1 = (const float*)d_in[10];
  const float* w_out = (const float*)d_in[11];
  const float* b_out = (const float*)d_in[12];

  char* ws = (char*)d_ws;
  unsigned short* ring0 = (unsigned short*)(ws + 0);            // 8 x 64KB
  unsigned short* ring1 = (unsigned short*)(ws + 524288);       // 8 x 64KB
  float* xg0  = (float*)(ws + 1048576);                         // 512KB
  float* h_in = (float*)(ws + 1572864);                         // 128KB
  int*   flags = (int*)(ws + 1703936);                          // 16KB

  hipMemsetAsync(flags, 0, 16384, stream);
  k_fc_in<<<64, 512, 0, stream>>>(x, w_in, b_in, h_in);
  k_xg0<<<256, 512, 0, stream>>>(h_in, w_ih0, b_ih0, b_hh0, xg0);
  lstm_persist<<<64, 512, 0, stream>>>(w_hh0, w_ih1, w_hh1, b_ih1, b_hh1,
                                       w_out, b_out, xg0, ring0, ring1,
                                       flags, (float*)d_out);
}

// Round 12
// 6332.791 us; speedup vs baseline: 1.1713x; 1.1713x over previous
//
#include <hip/hip_runtime.h>
#include <stdint.h>

// SingleBandLSTM: B=64, IN=16, H=512, T=1024, 2-layer LSTM, constant input per step.
// R12 = R10 (5963us, best) + ONE change: per-producer seq-word READY flags replace
// the shared RMW counters (32-way fetch_add fan-in on one LLC line serializes
// ~0.7-1.5us before the poller sees 32). Seq word = plain 4B sc1 store AFTER the
// publish-drain barrier (same data-before-flag protocol R10 proves); pollers read
// all 32 words (16B stride) with one wave-wide load + __all; L1 polls f0/f1
// CONCURRENTLY (lanes 0-31 / 32-63).
// Publishes stay R10's scattered 4B sc1 stores: R5/R7/R11 evidence shows u64 sc1
// stores get 4x write-amplified (WRITE_SIZE 137->532MB) and slow the drain.
// done/backpressure counters stay RMW (off the critical path).
// Kept from R10: coalesced 8x dwordx4 sc1 staging in ONE self-contained asm block,
// split L0/L1 blocks, ring depth 8, fused ih+hh MFMA, ((row&7)<<4) LDS swizzle.

#define TSEQ 1024
#define HDIM 512
#define BATCH 64
#define RING 8

typedef __attribute__((ext_vector_type(8))) short bf16x8;
typedef __attribute__((ext_vector_type(4))) float f32x4;
typedef __attribute__((ext_vector_type(4))) unsigned int u32x4;

__device__ __forceinline__ unsigned short f2bf(float f) {
  union { float f; unsigned u; } v; v.f = f;
  unsigned r = v.u + 0x7FFFu + ((v.u >> 16) & 1u);   // RNE
  return (unsigned short)(r >> 16);
}
__device__ __forceinline__ float bf2f(unsigned short s) {
  union { unsigned u; float f; } v; v.u = ((unsigned)s) << 16; return v.f;
}
__device__ __forceinline__ float sigm(float x) { return 1.0f / (1.0f + __expf(-x)); }
__device__ __forceinline__ float tanh_(float x) { return 1.0f - 2.0f / (__expf(2.0f * x) + 1.0f); }

__device__ __forceinline__ int g_ld32(const int* p) {
  return __hip_atomic_load(p, __ATOMIC_RELAXED, __HIP_MEMORY_SCOPE_AGENT);
}
__device__ __forceinline__ void g_st32(int* p, int v) {
  __hip_atomic_store(p, v, __ATOMIC_RELAXED, __HIP_MEMORY_SCOPE_AGENT);
}
__device__ __forceinline__ void flag_add(int* p) {
  __hip_atomic_fetch_add(p, 1, __ATOMIC_RELAXED, __HIP_MEMORY_SCOPE_AGENT);
}
__device__ __forceinline__ void flag_wait(int* p, int target) {
  while (g_ld32(p) < target) __builtin_amdgcn_s_sleep(1);
}
// Poll 32 per-producer seq words (16B stride): pass when all >= tgt. Wave-wide.
__device__ __forceinline__ void poll_seq(const int* f, int tgt, int lane) {
  const int* a = f + (lane & 31) * 4;
  while (!__all(g_ld32(a) >= tgt)) __builtin_amdgcn_s_sleep(1);
}
// L1 combined poll: lanes 0-31 check fa >= ta, lanes 32-63 check fb >= tb.
__device__ __forceinline__ void poll_seq2(const int* fa, int ta,
                                          const int* fb, int tb, int lane) {
  const int* a = (lane < 32) ? (fa + lane * 4) : (fb + (lane - 32) * 4);
  const int tgt = (lane < 32) ? ta : tb;
  while (!__all(g_ld32(a) >= tgt)) __builtin_amdgcn_s_sleep(1);
}

// 64KB global (bf16 [64][512] row-major) -> LDS, XOR swizzle ((row&7)<<4) on byte addr.
// LLC-coherent coalesced loads: 8x dwordx4 sc1 + vmcnt(0) in ONE asm block (R4-safe).
__device__ __forceinline__ void stage64k(char* lds, const unsigned short* src, int tid) {
  u32x4 r0, r1, r2, r3, r4, r5, r6, r7;
  const char* a = (const char*)src + (size_t)tid * 16;
  asm volatile(
      "global_load_dwordx4 %0, %8, off sc1\n\t"
      "global_load_dwordx4 %1, %9, off sc1\n\t"
      "global_load_dwordx4 %2, %10, off sc1\n\t"
      "global_load_dwordx4 %3, %11, off sc1\n\t"
      "global_load_dwordx4 %4, %12, off sc1\n\t"
      "global_load_dwordx4 %5, %13, off sc1\n\t"
      "global_load_dwordx4 %6, %14, off sc1\n\t"
      "global_load_dwordx4 %7, %15, off sc1\n\t"
      "s_waitcnt vmcnt(0)"
      : "=&v"(r0), "=&v"(r1), "=&v"(r2), "=&v"(r3),
        "=&v"(r4), "=&v"(r5), "=&v"(r6), "=&v"(r7)
      : "v"(a), "v"(a + 8192), "v"(a + 16384), "v"(a + 24576),
        "v"(a + 32768), "v"(a + 40960), "v"(a + 49152), "v"(a + 57344)
      : "memory");
  u32x4 vv[8] = {r0, r1, r2, r3, r4, r5, r6, r7};
  #pragma unroll
  for (int i = 0; i < 8; ++i) {
    int q = tid + i * 512;
    int row = q >> 6, kb = (q & 63) << 4;
    *(u32x4*)(lds + row * 1024 + (kb ^ ((row & 7) << 4))) = vv[i];
  }
}
__device__ __forceinline__ void zero64k(char* lds, int tid) {
  u32x4 z = {0u, 0u, 0u, 0u};
  #pragma unroll
  for (int i = 0; i < 8; ++i) {
    int q = tid + i * 512;
    int row = q >> 6, kb = (q & 63) << 4;
    *(u32x4*)(lds + row * 1024 + (kb ^ ((row & 7) << 4))) = z;
  }
}

// ---------------- precompute kernels ----------------
__global__ void k_fc_in(const float* __restrict__ x, const float* __restrict__ w_in,
                        const float* __restrict__ b_in, float* __restrict__ h_in) {
  int b = blockIdx.x;      // 64
  int j = threadIdx.x;     // 512
  float acc = b_in[j];
  #pragma unroll
  for (int i = 0; i < 16; ++i) acc += x[b * 16 + i] * w_in[j * 16 + i];
  h_in[b * HDIM + j] = acc;
}

__global__ __launch_bounds__(512, 1)
void k_xg0(const float* __restrict__ h_in, const float* __restrict__ w_ih0,
           const float* __restrict__ b_ih0, const float* __restrict__ b_hh0,
           float* __restrict__ xg0) {
  __shared__ float hbuf[64 * 516];
  __shared__ float wbuf[8 * 520];
  int r0 = blockIdx.x * 8;           // 256 blocks x 8 rows = 2048 gate rows
  int tid = threadIdx.x;
  for (int i = 0; i < 64; ++i) {
    int c = tid + i * 512;
    hbuf[(c >> 9) * 516 + (c & 511)] = h_in[c];
  }
  for (int i = 0; i < 8; ++i) {
    int c = tid + i * 512;
    wbuf[(c >> 9) * 520 + (c & 511)] = w_ih0[(size_t)r0 * HDIM + c];
  }
  __syncthreads();
  int b = tid >> 3, rl = tid & 7;
  float acc = 0.f;
  for (int k = 0; k < 512; ++k) acc += hbuf[b * 516 + k] * wbuf[rl * 520 + k];
  int r = r0 + rl;
  xg0[(size_t)b * 2048 + r] = acc + b_ih0[r] + b_hh0[r];
}

// ---------------- persistent recurrence kernel ----------------
__global__ __launch_bounds__(512, 1)
void lstm_persist(const float* __restrict__ w_hh0,
                  const float* __restrict__ w_ih1,
                  const float* __restrict__ w_hh1,
                  const float* __restrict__ b_ih1,
                  const float* __restrict__ b_hh1,
                  const float* __restrict__ w_out,
                  const float* __restrict__ b_out,
                  const float* __restrict__ xg0,
                  unsigned short* __restrict__ h0_ring,
                  unsigned short* __restrict__ h1_ring,
                  int* __restrict__ flags,
                  float* __restrict__ out) {
  __shared__ __align__(16) unsigned short hA[BATCH * HDIM];  // 64KB, swizzled
  __shared__ __align__(16) unsigned short hBt[BATCH * HDIM]; // 64KB, swizzled
  __shared__ float gbuf[BATCH * 68];                         // gate transpose buffer
  char* hAc = (char*)hA;
  char* hBc = (char*)hBt;

  const int tid = threadIdx.x;
  const int layer = blockIdx.x & 1;
  const int p = blockIdx.x >> 1;      // 0..31 within group
  const int u0 = p * 16;              // first owned hidden unit

  const int wave = tid >> 6, lane = tid & 63;
  const int nt = wave & 3;            // N-tile (16 gate rows)
  const int mh = wave >> 2;           // M-tile pair selector
  const int ln15 = lane & 15, lg = lane >> 4;

  const int n_local = nt * 16 + ln15;
  const int grow = (n_local & 3) * HDIM + u0 + (n_local >> 2);  // global gate row

  int* f0seq = flags;                 // 32 seq words x 16B stride (L0 ready)
  int* f1seq = flags + 128;           // 32 seq words x 16B stride (L1 ready)
  int* h0_done = flags + 256;         // TSEQ RMW counters (backpressure, off-path)
  int* h1_done = flags + 256 + TSEQ;

  // ---- weight fragments into registers (fp32 -> bf16) ----
  bf16x8 wh[16];  // w_hh (layer 0 or 1)
  bf16x8 wi[16];  // w_ih1 (layer 1 only)
  {
    const float* Wh = (layer == 0 ? w_hh0 : w_hh1) + (size_t)grow * HDIM;
    #pragma unroll
    for (int kt = 0; kt < 16; ++kt) {
      const float* s = Wh + kt * 32 + lg * 8;
      bf16x8 r;
      #pragma unroll
      for (int e = 0; e < 8; ++e) r[e] = (short)f2bf(s[e]);
      wh[kt] = r;
    }
  }
  if (layer == 1) {
    const float* Wi = w_ih1 + (size_t)grow * HDIM;
    #pragma unroll
    for (int kt = 0; kt < 16; ++kt) {
      const float* s = Wi + kt * 32 + lg * 8;
      bf16x8 r;
      #pragma unroll
      for (int e = 0; e < 8; ++e) r[e] = (short)f2bf(s[e]);
      wi[kt] = r;
    }
  }

  // ---- accumulator init (xg0 fragment for L0; bias for L1) ----
  f32x4 init0, init1;
  if (layer == 0) {
    #pragma unroll
    for (int r = 0; r < 4; ++r) {
      init0[r] = xg0[(size_t)(mh * 32 + lg * 4 + r) * 2048 + grow];
      init1[r] = xg0[(size_t)(mh * 32 + 16 + lg * 4 + r) * 2048 + grow];
    }
  } else {
    float bv = b_ih1[grow] + b_hh1[grow];
    #pragma unroll
    for (int r = 0; r < 4; ++r) { init0[r] = bv; init1[r] = bv; }
  }

  // cell state for this thread's two (batch,unit) pairs
  float c0 = 0.f, c1 = 0.f;
  const int pb = tid >> 3;            // batch of pair
  const int pu = (tid << 1) & 15;     // unit_local (even)

  const int r0 = mh * 32 + ln15, r1 = r0 + 16;
  const int x0 = (r0 & 7) << 4, x1 = (r1 & 7) << 4;

  if (layer == 0) {
    for (int t = 0; t < TSEQ; ++t) {
      if (t > 0 && wave == 0) poll_seq(f0seq, t, lane);
      __syncthreads();
      if (t > 0) {
        stage64k(hAc, h0_ring + (size_t)((t - 1) & (RING - 1)) * (BATCH * HDIM), tid);
        __syncthreads();
        if (tid == 0) flag_add(&h0_done[t - 1]);
      } else {
        zero64k(hAc, tid);
        __syncthreads();
      }
      f32x4 a0 = init0, a1 = init1;
      #pragma unroll
      for (int kt = 0; kt < 16; ++kt) {
        const int kb = kt * 64 + lg * 16;
        bf16x8 ha0 = *(const bf16x8*)(hAc + r0 * 1024 + (kb ^ x0));
        bf16x8 ha1 = *(const bf16x8*)(hAc + r1 * 1024 + (kb ^ x1));
        a0 = __builtin_amdgcn_mfma_f32_16x16x32_bf16(ha0, wh[kt], a0, 0, 0, 0);
        a1 = __builtin_amdgcn_mfma_f32_16x16x32_bf16(ha1, wh[kt], a1, 0, 0, 0);
      }
      #pragma unroll
      for (int r = 0; r < 4; ++r) {
        gbuf[(mh * 32 + lg * 4 + r) * 68 + n_local] = a0[r];
        gbuf[(mh * 32 + 16 + lg * 4 + r) * 68 + n_local] = a1[r];
      }
      if (t >= RING && tid == 0) flag_wait(&h0_done[t - RING], 64);
      __syncthreads();
      {
        f32x4 gA = *(const f32x4*)&gbuf[pb * 68 + pu * 4];
        f32x4 gB = *(const f32x4*)&gbuf[pb * 68 + pu * 4 + 4];
        float i0 = sigm(gA[0]), f0 = sigm(gA[1]), z0 = tanh_(gA[2]), o0 = sigm(gA[3]);
        float i1 = sigm(gB[0]), f1 = sigm(gB[1]), z1 = tanh_(gB[2]), o1 = sigm(gB[3]);
        c0 = f0 * c0 + i0 * z0;
        c1 = f1 * c1 + i1 * z1;
        float hv0 = o0 * tanh_(c0), hv1 = o1 * tanh_(c1);
        unsigned pk = (unsigned)f2bf(hv0) | ((unsigned)f2bf(hv1) << 16);
        unsigned short* slot = h0_ring + (size_t)(t & (RING - 1)) * (BATCH * HDIM);
        __hip_atomic_store((unsigned*)(slot + pb * HDIM + u0 + pu), pk,
                           __ATOMIC_RELAXED, __HIP_MEMORY_SCOPE_AGENT);
      }
      __syncthreads();   // implicit vmcnt(0): all sc1 h-stores visible at LLC
      if (tid == 0) g_st32(&f0seq[p * 4], t + 1);
    }
  } else {
    for (int t = 0; t < TSEQ; ++t) {
      // --- combined concurrent poll: f0 >= t+1 (lanes 0-31), f1 >= t (lanes 32-63) ---
      if (wave == 0) poll_seq2(f0seq, t + 1, f1seq, t, lane);
      __syncthreads();
      stage64k(hAc, h0_ring + (size_t)(t & (RING - 1)) * (BATCH * HDIM), tid);
      if (t > 0)
        stage64k(hBc, h1_ring + (size_t)((t - 1) & (RING - 1)) * (BATCH * HDIM), tid);
      else
        zero64k(hBc, tid);
      __syncthreads();
      if (tid == 0) {
        flag_add(&h0_done[t]);
        if (t > 0) flag_add(&h1_done[t - 1]);
      }

      // --- out_{t-1} from h1 tile (16 threads of wave 0; other waves proceed) ---
      if (t > 0 && tid < 16) {
        const int b = 2 * p + (tid >> 3), seg = tid & 7;
        const int xb = (b & 7) << 4;
        float acc = 0.f;
        #pragma unroll
        for (int i = 0; i < 8; ++i) {
          const int kb = seg * 128 + i * 16;
          bf16x8 hv = *(const bf16x8*)(hBc + b * 1024 + (kb ^ xb));
          const float* wo = w_out + (kb >> 1);
          #pragma unroll
          for (int e = 0; e < 8; ++e) acc += bf2f((unsigned short)hv[e]) * wo[e];
        }
        acc += __shfl_down(acc, 4, 8);
        acc += __shfl_down(acc, 2, 8);
        acc += __shfl_down(acc, 1, 8);
        if (seg == 0) out[b * TSEQ + (t - 1)] = acc + b_out[0];
      }

      // --- fused ih (from h0 tile) + hh (from h1 tile) MFMA loop ---
      f32x4 a0 = init0, a1 = init1;
      #pragma unroll
      for (int kt = 0; kt < 16; ++kt) {
        const int kb = kt * 64 + lg * 16;
        bf16x8 ia0 = *(const bf16x8*)(hAc + r0 * 1024 + (kb ^ x0));
        bf16x8 ia1 = *(const bf16x8*)(hAc + r1 * 1024 + (kb ^ x1));
        bf16x8 ha0 = *(const bf16x8*)(hBc + r0 * 1024 + (kb ^ x0));
        bf16x8 ha1 = *(const bf16x8*)(hBc + r1 * 1024 + (kb ^ x1));
        a0 = __builtin_amdgcn_mfma_f32_16x16x32_bf16(ia0, wi[kt], a0, 0, 0, 0);
        a1 = __builtin_amdgcn_mfma_f32_16x16x32_bf16(ia1, wi[kt], a1, 0, 0, 0);
        a0 = __builtin_amdgcn_mfma_f32_16x16x32_bf16(ha0, wh[kt], a0, 0, 0, 0);
        a1 = __builtin_amdgcn_mfma_f32_16x16x32_bf16(ha1, wh[kt], a1, 0, 0, 0);
      }
      #pragma unroll
      for (int r = 0; r < 4; ++r) {
        gbuf[(mh * 32 + lg * 4 + r) * 68 + n_local] = a0[r];
        gbuf[(mh * 32 + 16 + lg * 4 + r) * 68 + n_local] = a1[r];
      }
      if (t >= RING && tid == 0) flag_wait(&h1_done[t - RING], 32);
      __syncthreads();
      {
        f32x4 gA = *(const f32x4*)&gbuf[pb * 68 + pu * 4];
        f32x4 gB = *(const f32x4*)&gbuf[pb * 68 + pu * 4 + 4];
        float i0 = sigm(gA[0]), f0 = sigm(gA[1]), z0 = tanh_(gA[2]), o0 = sigm(gA[3]);
        float i1 = sigm(gB[0]), f1 = sigm(gB[1]), z1 = tanh_(gB[2]), o1 = sigm(gB[3]);
        c0 = f0 * c0 + i0 * z0;
        c1 = f1 * c1 + i1 * z1;
        float hv0 = o0 * tanh_(c0), hv1 = o1 * tanh_(c1);
        unsigned pk = (unsigned)f2bf(hv0) | ((unsigned)f2bf(hv1) << 16);
        unsigned short* slot = h1_ring + (size_t)(t & (RING - 1)) * (BATCH * HDIM);
        __hip_atomic_store((unsigned*)(slot + pb * HDIM + u0 + pu), pk,
                           __ATOMIC_RELAXED, __HIP_MEMORY_SCOPE_AGENT);
      }
      __syncthreads();   // implicit vmcnt(0): all sc1 h-stores visible at LLC
      if (tid == 0) g_st32(&f1seq[p * 4], t + 1);
    }
    // epilogue: out_{T-1}
    if (wave == 0) poll_seq(f1seq, TSEQ, lane);
    __syncthreads();
    stage64k(hBc, h1_ring + (size_t)((TSEQ - 1) & (RING - 1)) * (BATCH * HDIM), tid);
    __syncthreads();
    if (tid < 16) {
      const int b = 2 * p + (tid >> 3), seg = tid & 7;
      const int xb = (b & 7) << 4;
      float acc = 0.f;
      #pragma unroll
      for (int i = 0; i < 8; ++i) {
        const int kb = seg * 128 + i * 16;
        bf16x8 hv = *(const bf16x8*)(hBc + b * 1024 + (kb ^ xb));
        const float* wo = w_out + (kb >> 1);
        #pragma unroll
        for (int e = 0; e < 8; ++e) acc += bf2f((unsigned short)hv[e]) * wo[e];
      }
      acc += __shfl_down(acc, 4, 8);
      acc += __shfl_down(acc, 2, 8);
      acc += __shfl_down(acc, 1, 8);
      if (seg == 0) out[b * TSEQ + (TSEQ - 1)] = acc + b_out[0];
    }
  }
}

extern "C" void kernel_launch(void* const* d_in, const int* in_sizes, int n_in,
                              void* d_out, int out_size, void* d_ws, size_t ws_size,
                              hipStream_t stream) {
  (void)in_sizes; (void)n_in; (void)out_size; (void)ws_size;
  const float* x     = (const float*)d_in[0];
  const float* w_in  = (const float*)d_in[1];
  const float* b_in  = (const float*)d_in[2];
  const float* w_ih0 = (const float*)d_in[3];
  const float* w_hh0 = (const float*)d_in[4];
  const float* b_ih0 = (const float*)d_in[5];
  const float* b_hh0 = (const float*)d_in[6];
  const float* w_ih1 = (const float*)d_in[7];
  const float* w_hh1 = (const float*)d_in[8];
  const float* b_ih1 = (const float*)d_in[9];
  const float* b_hh1 = (const float*)d_in[10];
  const float* w_out = (const float*)d_in[11];
  const float* b_out = (const float*)d_in[12];

  char* ws = (char*)d_ws;
  unsigned short* h0_ring = (unsigned short*)(ws + 0);          // 512KB
  unsigned short* h1_ring = (unsigned short*)(ws + 524288);     // 512KB
  float* xg0  = (float*)(ws + 1048576);                         // 512KB
  float* h_in = (float*)(ws + 1572864);                         // 128KB
  int*   flags = (int*)(ws + 1703936);                          // 16KB

  hipMemsetAsync(flags, 0, 16384, stream);
  k_fc_in<<<64, 512, 0, stream>>>(x, w_in, b_in, h_in);
  k_xg0<<<256, 512, 0, stream>>>(h_in, w_ih0, b_ih0, b_hh0, xg0);
  lstm_persist<<<64, 512, 0, stream>>>(w_hh0, w_ih1, w_hh1, b_ih1, b_hh1,
                                       w_out, b_out, xg0, h0_ring, h1_ring,
                                       flags, (float*)d_out);
}